// Round 8
// baseline (168.815 us; speedup 1.0000x reference)
//
#include <hip/hip_runtime.h>
#include <hip/hip_bf16.h>

#define DIM 128
#define NSUB 8        // XCD-exclusive sub-CSRs (sub = blockIdx.x & 7, round-robin proxy)

#define SCAN_TPB 256
#define SCAN_EPT 4
#define SCAN_CHUNK (SCAN_TPB * SCAN_EPT)   // 1024 elements per scan block

// finish kernel geometry
#define FROWS 64      // M-tile rows per block
#define FPAD 136      // bf16 row stride in LDS: 272B -> 2-way bank alias on b128 (free)

typedef __attribute__((ext_vector_type(8))) short bf16x8;
typedef __attribute__((ext_vector_type(8))) unsigned short u16x8;
typedef __attribute__((ext_vector_type(4))) float f32x4;

__device__ __forceinline__ short f2bf(float f) {
    union { __hip_bfloat16 h; short s; } u;
    u.h = __float2bfloat16(f);   // round-to-nearest-even
    return u.s;
}
__device__ __forceinline__ float bf2f(unsigned short s) {
    union { unsigned int u; float f; } c;
    c.u = ((unsigned int)s) << 16;
    return c.f;
}

// ---------------------------------------------------------------------------
// Prep (fused): zero cnt+cursor, cvt x f32 -> xb bf16, detect int64/int32
// edge index (values < 2^17 => int64 high words of first 128 entries all 0).
// ---------------------------------------------------------------------------
__global__ __launch_bounds__(256) void prep_kernel(
        const float* __restrict__ x, unsigned short* __restrict__ xb, int n8,
        int* __restrict__ p, int nzero,
        const unsigned int* __restrict__ e, int* __restrict__ flags) {
    int stride = gridDim.x * blockDim.x;
    int t0 = blockIdx.x * blockDim.x + threadIdx.x;
    for (int t = t0; t < nzero; t += stride) p[t] = 0;
    for (int t = t0; t < n8; t += stride) {
        const float4* pp = (const float4*)(x + (size_t)t * 8);
        float4 a = pp[0], b = pp[1];
        u16x8 o;
        o[0] = (unsigned short)f2bf(a.x); o[1] = (unsigned short)f2bf(a.y);
        o[2] = (unsigned short)f2bf(a.z); o[3] = (unsigned short)f2bf(a.w);
        o[4] = (unsigned short)f2bf(b.x); o[5] = (unsigned short)f2bf(b.y);
        o[6] = (unsigned short)f2bf(b.z); o[7] = (unsigned short)f2bf(b.w);
        *(u16x8*)(xb + (size_t)t * 8) = o;
    }
    if (blockIdx.x == 0 && threadIdx.x == 0) {
        int ok64 = 1;
        for (int t = 0; t < 128; ++t) {
            if (e[2 * t + 1] != 0u) { ok64 = 0; break; }
        }
        flags[0] = ok64;
    }
}

__device__ __forceinline__ int load_dst(const void* eidx, int flag64, int E, int e) {
    return flag64 ? (int)((const long long*)eidx)[E + e] : ((const int*)eidx)[E + e];
}
__device__ __forceinline__ int load_src(const void* eidx, int flag64, int E, int e) {
    return flag64 ? (int)((const long long*)eidx)[e] : ((const int*)eidx)[e];
}

// ---------------------------------------------------------------------------
// CSR build over NSUB XCD-exclusive sub-bins: hist -> scan (sub-major) -> fill
// ---------------------------------------------------------------------------
__global__ void hist_kernel(const void* __restrict__ eidx, int* __restrict__ cnt,
                            const int* __restrict__ flags, int E, int nn) {
    int e = blockIdx.x * blockDim.x + threadIdx.x;
    if (e >= E) return;
    int sub = blockIdx.x & (NSUB - 1);
    atomicAdd(&cnt[sub * nn + load_dst(eidx, flags[0], E, e)], 1);
}

__global__ __launch_bounds__(SCAN_TPB) void scan1_kernel(
        const int* __restrict__ cnt, int* __restrict__ rowstart,
        int* __restrict__ blockSums, int ntot) {
    __shared__ int s[SCAN_TPB];
    const int base = blockIdx.x * SCAN_CHUNK;
    const int tid = threadIdx.x;
    int v[SCAN_EPT];
    int tsum = 0;
    #pragma unroll
    for (int u = 0; u < SCAN_EPT; ++u) {
        int i = base + tid * SCAN_EPT + u;
        int c = (i < ntot) ? cnt[i] : 0;
        v[u] = tsum;
        tsum += c;
    }
    s[tid] = tsum;
    __syncthreads();
    for (int off = 1; off < SCAN_TPB; off <<= 1) {
        int t = (tid >= off) ? s[tid - off] : 0;
        __syncthreads();
        s[tid] += t;
        __syncthreads();
    }
    int ex = s[tid] - tsum;
    #pragma unroll
    for (int u = 0; u < SCAN_EPT; ++u) {
        int i = base + tid * SCAN_EPT + u;
        if (i < ntot) rowstart[i] = ex + v[u];
    }
    if (tid == SCAN_TPB - 1) blockSums[blockIdx.x] = s[tid];
}

__global__ __launch_bounds__(1024) void scan2_kernel(
        const int* __restrict__ blockSums, int* __restrict__ blockOff, int nb) {
    __shared__ int s[1024];
    int tid = threadIdx.x;
    int val = (tid < nb) ? blockSums[tid] : 0;
    s[tid] = val;
    __syncthreads();
    for (int off = 1; off < 1024; off <<= 1) {
        int t = (tid >= off) ? s[tid - off] : 0;
        __syncthreads();
        s[tid] += t;
        __syncthreads();
    }
    if (tid < nb) blockOff[tid] = s[tid] - val;
}

__global__ __launch_bounds__(SCAN_TPB) void scan3_kernel(
        int* __restrict__ rowstart, const int* __restrict__ blockOff, int ntot, int E) {
    const int base = blockIdx.x * SCAN_CHUNK;
    const int off = blockOff[blockIdx.x];
    #pragma unroll
    for (int u = 0; u < SCAN_EPT; ++u) {
        int i = base + threadIdx.x + u * SCAN_TPB;
        if (i < ntot) rowstart[i] += off;
    }
    if (blockIdx.x == 0 && threadIdx.x == 0) rowstart[ntot] = E;
}

// Writes into sub-region (blockIdx&7) come only from blocks on one XCD under
// round-robin dispatch -> no cross-XCD dirty-line sharing -> no 8x write amp.
__global__ void fill_kernel(const void* __restrict__ eidx, const float* __restrict__ ew,
                            const int* __restrict__ rowstart, int* __restrict__ cursor,
                            uint2* __restrict__ srcw, const int* __restrict__ flags,
                            int E, int nn) {
    int e = blockIdx.x * blockDim.x + threadIdx.x;
    if (e >= E) return;
    int sub = blockIdx.x & (NSUB - 1);
    int f = flags[0];
    int src = load_src(eidx, f, E, e);
    int dst = load_dst(eidx, f, E, e);
    int bin = sub * nn + dst;
    int pos = rowstart[bin] + atomicAdd(&cursor[bin], 1);
    uint2 p;
    p.x = (unsigned)src;
    p.y = __float_as_uint(ew[e]);
    srcw[pos] = p;
}

// ---------------------------------------------------------------------------
// Gather: ONE WAVE PER NODE. Lane group sb = lanes [8sb, 8sb+8) walks
// sub-segment sb in parallel; lane owns 16 dims (32B) -> each group covers
// all 128 dims of its edges. 8 segments processed concurrently (8 row
// fetches in flight), then 3-round shfl_xor butterfly (8/16/32: group bits
// only; dim ownership = lane&7 is xor-invariant) sums partials + deg.
// Lanes 0-7 write one contiguous 256B bf16 row. No atomics.
// ---------------------------------------------------------------------------
__global__ __launch_bounds__(256) void gather_kernel(
        const unsigned short* __restrict__ xb, const uint2* __restrict__ srcw,
        const int* __restrict__ rowstart, unsigned short* __restrict__ aggb, int nn) {
    int g = (blockIdx.x * blockDim.x + threadIdx.x) >> 6;   // node = global wave id
    if (g >= nn) return;                                     // wave-uniform
    const int lane = threadIdx.x & 63;
    const int sb = lane >> 3;          // sub-segment handled by this group
    const int sl = lane & 7;           // owns dims [sl*16, sl*16+16)

    int n0 = rowstart[sb * nn + g];
    int n1 = rowstart[sb * nn + g + 1];   // flattened sub-major scan is continuous

    float acc[16];
    #pragma unroll
    for (int j = 0; j < 16; ++j) acc[j] = 0.f;

    for (int e = n0; e < n1; ++e) {
        uint2 sw = srcw[e];                                   // broadcast in group
        float w = __uint_as_float(sw.y);
        const u16x8* xp = (const u16x8*)(xb + (size_t)sw.x * DIM + sl * 16);
        u16x8 x0 = xp[0], x1 = xp[1];
        #pragma unroll
        for (int j = 0; j < 8; ++j) {
            acc[j]     = fmaf(bf2f(x0[j]), w, acc[j]);
            acc[j + 8] = fmaf(bf2f(x1[j]), w, acc[j + 8]);
        }
    }
    float dcount = (float)(n1 - n0);

    // butterfly across the 8 groups (lane bits 3..5)
    #pragma unroll
    for (int st = 8; st < 64; st <<= 1) {
        #pragma unroll
        for (int j = 0; j < 16; ++j) acc[j] += __shfl_xor(acc[j], st);
        dcount += __shfl_xor(dcount, st);
    }

    float inv = 1.0f / fmaxf(dcount, 1.0f);
    if (lane < 8) {
        u16x8 o0, o1;
        #pragma unroll
        for (int j = 0; j < 8; ++j) {
            o0[j] = (unsigned short)f2bf(acc[j] * inv);
            o1[j] = (unsigned short)f2bf(acc[j + 8] * inv);
        }
        u16x8* op = (u16x8*)(aggb + (size_t)g * DIM + lane * 16);
        op[0] = o0;
        op[1] = o1;
    }
}

// ---------------------------------------------------------------------------
// MFMA finish: out = x + alpha*(aggb @ W^T + b). aggb is bf16 in ws; out is
// d_out (overwrites the xb scratch parked there, which is dead by now).
// 512 threads = 8 waves; 64-row M-tile; wave w owns output cols [16w,16w+16).
// C/D map: col=lane&15, row=(lane>>4)*4+reg  [verified, learn_hip m89/m91]
// ---------------------------------------------------------------------------
__global__ __launch_bounds__(512) void finish_kernel(
        const unsigned short* __restrict__ aggb, float* __restrict__ out,
        const float* __restrict__ x, const float* __restrict__ W,
        const float* __restrict__ bias, const float* __restrict__ alphaP, int nn) {
    __shared__ alignas(16) unsigned short A_lds[FROWS * FPAD];   // 17408 B
    const int tid  = threadIdx.x;
    const int wv   = tid >> 6;          // wave 0..7
    const int lane = tid & 63;
    const int half = lane >> 4;         // 0..3 (K-group / row-group)
    const int l16  = lane & 15;         // M-row for A, N-col for B and C/D
    const int b0   = blockIdx.x * FROWS;
    const float alpha = alphaP[0];

    // ---- B-frags: W[jcol][kt*32 + half*8 .. +8] as bf16, loaded once ----
    const int jcol = wv * 16 + l16;
    bf16x8 bfrag[4];
    #pragma unroll
    for (int kt = 0; kt < 4; ++kt) {
        const float4* w4 = (const float4*)(W + (size_t)jcol * DIM + kt * 32 + half * 8);
        float4 lo = w4[0], hi = w4[1];
        bf16x8 b;
        b[0] = f2bf(lo.x); b[1] = f2bf(lo.y); b[2] = f2bf(lo.z); b[3] = f2bf(lo.w);
        b[4] = f2bf(hi.x); b[5] = f2bf(hi.y); b[6] = f2bf(hi.z); b[7] = f2bf(hi.w);
        bfrag[kt] = b;
    }
    const float bias_j = bias[jcol];

    // ---- stage 64 bf16 rows -> LDS: 1024 chunks of 16B, 2 iters ----
    #pragma unroll
    for (int it = 0; it < 2; ++it) {
        int p = it * 512 + tid;          // 0..1023
        int row = p >> 4;                // 0..63
        int c8 = p & 15;                 // 16B chunk within row
        int node = b0 + row;
        u16x8 v = {0, 0, 0, 0, 0, 0, 0, 0};
        if (node < nn) v = *(const u16x8*)(aggb + (size_t)node * DIM + c8 * 8);
        *(u16x8*)&A_lds[row * FPAD + c8 * 8] = v;
    }
    __syncthreads();

    // ---- 4 sub-tiles of 16 rows: MFMA + fused epilogue ----
    #pragma unroll
    for (int mt = 0; mt < 4; ++mt) {
        f32x4 acc = {0.f, 0.f, 0.f, 0.f};
        #pragma unroll
        for (int kt = 0; kt < 4; ++kt) {
            const bf16x8 a = *(const bf16x8*)&A_lds[(mt * 16 + l16) * FPAD + kt * 32 + half * 8];
            acc = __builtin_amdgcn_mfma_f32_16x16x32_bf16(a, bfrag[kt], acc, 0, 0, 0);
        }
        #pragma unroll
        for (int r = 0; r < 4; ++r) {
            int grow = b0 + mt * 16 + half * 4 + r;
            if (grow < nn) {
                size_t idx = (size_t)grow * DIM + jcol;
                out[idx] = x[idx] + alpha * (acc[r] + bias_j);
            }
        }
    }
}

extern "C" void kernel_launch(void* const* d_in, const int* in_sizes, int n_in,
                              void* d_out, int out_size, void* d_ws, size_t ws_size,
                              hipStream_t stream) {
    // inputs: x(0), edge_index(1), num_nodes(2), edge_weight(3), W(4), b(5), alpha(6)
    const float* x      = (const float*)d_in[0];
    const void*  eidx   = d_in[1];
    const float* ew     = (const float*)d_in[3];
    const float* W      = (const float*)d_in[4];
    const float* bias   = (const float*)d_in[5];
    const float* alphaP = (const float*)d_in[6];

    const int NN = in_sizes[0] / DIM;
    const int E  = in_sizes[3];
    const int NTOT = NSUB * NN;     // 800K bins

    // ws layout: aggb u16[NN*DIM] (25.6MB) | srcw uint2[E] (5.1MB)
    //            | cnt int[NTOT] | cursor int[NTOT] | rowstart int[NTOT+1]
    //            | blockSums[1024] | blockOff[1024] | flags[2]   (~41 MB)
    unsigned short* aggb = (unsigned short*)d_ws;
    uint2* srcw      = (uint2*)(aggb + (size_t)NN * DIM);
    int*   cnt       = (int*)(srcw + E);
    int*   cursor    = cnt + NTOT;
    int*   rowstart  = cursor + NTOT;
    int*   blockSums = rowstart + NTOT + 1;
    int*   blockOff  = blockSums + 1024;
    int*   flags     = blockOff + 1024;

    // xb (bf16 copy of x) parks in the first half of d_out; dead once finish runs
    unsigned short* xb = (unsigned short*)d_out;
    float* out = (float*)d_out;

    int n8 = NN * DIM / 8;
    prep_kernel<<<2048, 256, 0, stream>>>(x, xb, n8, cnt, 2 * NTOT,
                                          (const unsigned int*)eidx, flags);

    int eblocks = (E + 255) / 256;
    hist_kernel<<<eblocks, 256, 0, stream>>>(eidx, cnt, flags, E, NN);

    int nscan8 = (NTOT + SCAN_CHUNK - 1) / SCAN_CHUNK;          // 782
    scan1_kernel<<<nscan8, SCAN_TPB, 0, stream>>>(cnt, rowstart, blockSums, NTOT);
    scan2_kernel<<<1, 1024, 0, stream>>>(blockSums, blockOff, nscan8);
    scan3_kernel<<<nscan8, SCAN_TPB, 0, stream>>>(rowstart, blockOff, NTOT, E);

    fill_kernel<<<eblocks, 256, 0, stream>>>(eidx, ew, rowstart, cursor, srcw, flags, E, NN);

    int gblocks = (NN + 3) / 4;                                  // 1 node/wave, 4 waves/block
    gather_kernel<<<gblocks, 256, 0, stream>>>(xb, srcw, rowstart, aggb, NN);

    int fblocks = (NN + FROWS - 1) / FROWS;
    finish_kernel<<<fblocks, 512, 0, stream>>>(aggb, out, x, W, bias, alphaP, NN);
}

// Round 9
// 150.556 us; speedup vs baseline: 1.1213x; 1.1213x over previous
//
#include <hip/hip_runtime.h>
#include <hip/hip_bf16.h>

#define DIM 128

#define SCAN_TPB 256
#define SCAN_EPT 4
#define SCAN_CHUNK (SCAN_TPB * SCAN_EPT)   // 1024 elements per scan block

// finish kernel geometry
#define FROWS 64      // M-tile rows per block
#define FPAD 136      // bf16 row stride in LDS: 272B -> 2-way bank alias on b128 (free)

typedef __attribute__((ext_vector_type(8))) short bf16x8;
typedef __attribute__((ext_vector_type(8))) unsigned short u16x8;
typedef __attribute__((ext_vector_type(4))) float f32x4;

__device__ __forceinline__ short f2bf(float f) {
    union { __hip_bfloat16 h; short s; } u;
    u.h = __float2bfloat16(f);   // round-to-nearest-even
    return u.s;
}
__device__ __forceinline__ float bf2f(unsigned short s) {
    union { unsigned int u; float f; } c;
    c.u = ((unsigned int)s) << 16;
    return c.f;
}

// ---------------------------------------------------------------------------
// Prep (fused): zero cnt+cursor, cvt x f32 -> xb bf16, detect int64/int32
// edge index (values < 2^17 => int64 high words of first 128 entries all 0).
// ---------------------------------------------------------------------------
__global__ __launch_bounds__(256) void prep_kernel(
        const float* __restrict__ x, unsigned short* __restrict__ xb, int n8,
        int* __restrict__ p, int nzero,
        const unsigned int* __restrict__ e, int* __restrict__ flags) {
    int stride = gridDim.x * blockDim.x;
    int t0 = blockIdx.x * blockDim.x + threadIdx.x;
    for (int t = t0; t < nzero; t += stride) p[t] = 0;
    for (int t = t0; t < n8; t += stride) {
        const float4* pp = (const float4*)(x + (size_t)t * 8);
        float4 a = pp[0], b = pp[1];
        u16x8 o;
        o[0] = (unsigned short)f2bf(a.x); o[1] = (unsigned short)f2bf(a.y);
        o[2] = (unsigned short)f2bf(a.z); o[3] = (unsigned short)f2bf(a.w);
        o[4] = (unsigned short)f2bf(b.x); o[5] = (unsigned short)f2bf(b.y);
        o[6] = (unsigned short)f2bf(b.z); o[7] = (unsigned short)f2bf(b.w);
        *(u16x8*)(xb + (size_t)t * 8) = o;
    }
    if (blockIdx.x == 0 && threadIdx.x == 0) {
        int ok64 = 1;
        for (int t = 0; t < 128; ++t) {
            if (e[2 * t + 1] != 0u) { ok64 = 0; break; }
        }
        flags[0] = ok64;
    }
}

__device__ __forceinline__ int load_dst(const void* eidx, int flag64, int E, int e) {
    return flag64 ? (int)((const long long*)eidx)[E + e] : ((const int*)eidx)[E + e];
}
__device__ __forceinline__ int load_src(const void* eidx, int flag64, int E, int e) {
    return flag64 ? (int)((const long long*)eidx)[e] : ((const int*)eidx)[e];
}

// ---------------------------------------------------------------------------
// CSR build, unified node-major: hist -> scan1 -> scan2 (block offsets only;
// consumers add blockOff[bin>>10] themselves) -> fill with NON-TEMPORAL
// stores (no L2 allocate -> no cross-XCD dirty-line sharing -> no write amp).
// ---------------------------------------------------------------------------
__global__ void hist_kernel(const void* __restrict__ eidx, int* __restrict__ cnt,
                            const int* __restrict__ flags, int E) {
    int e = blockIdx.x * blockDim.x + threadIdx.x;
    if (e >= E) return;
    atomicAdd(&cnt[load_dst(eidx, flags[0], E, e)], 1);
}

__global__ __launch_bounds__(SCAN_TPB) void scan1_kernel(
        const int* __restrict__ cnt, int* __restrict__ rowstart,
        int* __restrict__ blockSums, int ntot) {
    __shared__ int s[SCAN_TPB];
    const int base = blockIdx.x * SCAN_CHUNK;
    const int tid = threadIdx.x;
    int v[SCAN_EPT];
    int tsum = 0;
    #pragma unroll
    for (int u = 0; u < SCAN_EPT; ++u) {
        int i = base + tid * SCAN_EPT + u;
        int c = (i < ntot) ? cnt[i] : 0;
        v[u] = tsum;
        tsum += c;
    }
    s[tid] = tsum;
    __syncthreads();
    for (int off = 1; off < SCAN_TPB; off <<= 1) {
        int t = (tid >= off) ? s[tid - off] : 0;
        __syncthreads();
        s[tid] += t;
        __syncthreads();
    }
    int ex = s[tid] - tsum;
    #pragma unroll
    for (int u = 0; u < SCAN_EPT; ++u) {
        int i = base + tid * SCAN_EPT + u;
        if (i < ntot) rowstart[i] = ex + v[u];
    }
    if (tid == SCAN_TPB - 1) blockSums[blockIdx.x] = s[tid];
}

__global__ __launch_bounds__(1024) void scan2_kernel(
        const int* __restrict__ blockSums, int* __restrict__ blockOff, int nb) {
    __shared__ int s[1024];
    int tid = threadIdx.x;
    int val = (tid < nb) ? blockSums[tid] : 0;
    s[tid] = val;
    __syncthreads();
    for (int off = 1; off < 1024; off <<= 1) {
        int t = (tid >= off) ? s[tid - off] : 0;
        __syncthreads();
        s[tid] += t;
        __syncthreads();
    }
    if (tid < nb) blockOff[tid] = s[tid] - val;   // exclusive
}

// pos = rowstart[dst] + blockOff[dst>>10] + cursor++; nt store of packed (w,src)
__global__ void fill_kernel(const void* __restrict__ eidx, const float* __restrict__ ew,
                            const int* __restrict__ rowstart, const int* __restrict__ blockOff,
                            int* __restrict__ cursor, unsigned long long* __restrict__ srcw,
                            const int* __restrict__ flags, int E) {
    int e = blockIdx.x * blockDim.x + threadIdx.x;
    if (e >= E) return;
    int f = flags[0];
    int src = load_src(eidx, f, E, e);
    int dst = load_dst(eidx, f, E, e);
    int pos = rowstart[dst] + blockOff[dst >> 10] + atomicAdd(&cursor[dst], 1);
    unsigned long long pk = ((unsigned long long)__float_as_uint(ew[e]) << 32)
                          | (unsigned long long)(unsigned)src;
    __builtin_nontemporal_store(pk, &srcw[pos]);
}

// ---------------------------------------------------------------------------
// Gather: 4 nodes per wave (16 lanes per node, lane owns 8 dims = 16B bf16).
// Unified contiguous segment per node; 4-edge unroll -> up to 16 row-fetches
// in flight per wave. No atomics, no butterflies.
// ---------------------------------------------------------------------------
__global__ __launch_bounds__(256) void gather_kernel(
        const unsigned short* __restrict__ xb, const uint2* __restrict__ srcw,
        const int* __restrict__ rowstart, const int* __restrict__ blockOff,
        unsigned short* __restrict__ aggb, int nn, int E) {
    int g = (blockIdx.x * blockDim.x + threadIdx.x) >> 4;   // node
    int sub16 = threadIdx.x & 15;                           // owns dims [8*sub16, +8)
    if (g >= nn) return;
    int n0 = rowstart[g] + blockOff[g >> 10];
    int n1 = (g + 1 < nn) ? rowstart[g + 1] + blockOff[(g + 1) >> 10] : E;
    float acc[8] = {0.f, 0.f, 0.f, 0.f, 0.f, 0.f, 0.f, 0.f};
    int e = n0;
    for (; e + 4 <= n1; e += 4) {
        uint2 sw0 = srcw[e];
        uint2 sw1 = srcw[e + 1];
        uint2 sw2 = srcw[e + 2];
        uint2 sw3 = srcw[e + 3];
        u16x8 x0 = *(const u16x8*)(xb + (size_t)sw0.x * DIM + sub16 * 8);
        u16x8 x1 = *(const u16x8*)(xb + (size_t)sw1.x * DIM + sub16 * 8);
        u16x8 x2 = *(const u16x8*)(xb + (size_t)sw2.x * DIM + sub16 * 8);
        u16x8 x3 = *(const u16x8*)(xb + (size_t)sw3.x * DIM + sub16 * 8);
        float w0 = __uint_as_float(sw0.y);
        float w1 = __uint_as_float(sw1.y);
        float w2 = __uint_as_float(sw2.y);
        float w3 = __uint_as_float(sw3.y);
        #pragma unroll
        for (int j = 0; j < 8; ++j) {
            acc[j] = fmaf(bf2f(x0[j]), w0, acc[j]);
            acc[j] = fmaf(bf2f(x1[j]), w1, acc[j]);
            acc[j] = fmaf(bf2f(x2[j]), w2, acc[j]);
            acc[j] = fmaf(bf2f(x3[j]), w3, acc[j]);
        }
    }
    for (; e < n1; ++e) {
        uint2 sw = srcw[e];
        u16x8 xr = *(const u16x8*)(xb + (size_t)sw.x * DIM + sub16 * 8);
        float w = __uint_as_float(sw.y);
        #pragma unroll
        for (int j = 0; j < 8; ++j) acc[j] = fmaf(bf2f(xr[j]), w, acc[j]);
    }
    float inv = 1.0f / fmaxf((float)(n1 - n0), 1.0f);
    u16x8 o;
    #pragma unroll
    for (int j = 0; j < 8; ++j) o[j] = (unsigned short)f2bf(acc[j] * inv);
    *(u16x8*)(aggb + (size_t)g * DIM + sub16 * 8) = o;
}

// ---------------------------------------------------------------------------
// MFMA finish: out = x + alpha*(aggb @ W^T + b). aggb is bf16 in ws; out is
// d_out (overwrites the xb scratch parked there, which is dead by now).
// 512 threads = 8 waves; 64-row M-tile; wave w owns output cols [16w,16w+16).
// C/D map: col=lane&15, row=(lane>>4)*4+reg  [verified, learn_hip m89/m91]
// ---------------------------------------------------------------------------
__global__ __launch_bounds__(512) void finish_kernel(
        const unsigned short* __restrict__ aggb, float* __restrict__ out,
        const float* __restrict__ x, const float* __restrict__ W,
        const float* __restrict__ bias, const float* __restrict__ alphaP, int nn) {
    __shared__ alignas(16) unsigned short A_lds[FROWS * FPAD];   // 17408 B
    const int tid  = threadIdx.x;
    const int wv   = tid >> 6;          // wave 0..7
    const int lane = tid & 63;
    const int half = lane >> 4;         // 0..3 (K-group / row-group)
    const int l16  = lane & 15;         // M-row for A, N-col for B and C/D
    const int b0   = blockIdx.x * FROWS;
    const float alpha = alphaP[0];

    // ---- B-frags: W[jcol][kt*32 + half*8 .. +8] as bf16, loaded once ----
    const int jcol = wv * 16 + l16;
    bf16x8 bfrag[4];
    #pragma unroll
    for (int kt = 0; kt < 4; ++kt) {
        const float4* w4 = (const float4*)(W + (size_t)jcol * DIM + kt * 32 + half * 8);
        float4 lo = w4[0], hi = w4[1];
        bf16x8 b;
        b[0] = f2bf(lo.x); b[1] = f2bf(lo.y); b[2] = f2bf(lo.z); b[3] = f2bf(lo.w);
        b[4] = f2bf(hi.x); b[5] = f2bf(hi.y); b[6] = f2bf(hi.z); b[7] = f2bf(hi.w);
        bfrag[kt] = b;
    }
    const float bias_j = bias[jcol];

    // ---- stage 64 bf16 rows -> LDS: 1024 chunks of 16B, 2 iters ----
    #pragma unroll
    for (int it = 0; it < 2; ++it) {
        int p = it * 512 + tid;          // 0..1023
        int row = p >> 4;                // 0..63
        int c8 = p & 15;                 // 16B chunk within row
        int node = b0 + row;
        u16x8 v = {0, 0, 0, 0, 0, 0, 0, 0};
        if (node < nn) v = *(const u16x8*)(aggb + (size_t)node * DIM + c8 * 8);
        *(u16x8*)&A_lds[row * FPAD + c8 * 8] = v;
    }
    __syncthreads();

    // ---- 4 sub-tiles of 16 rows: MFMA + fused epilogue ----
    #pragma unroll
    for (int mt = 0; mt < 4; ++mt) {
        f32x4 acc = {0.f, 0.f, 0.f, 0.f};
        #pragma unroll
        for (int kt = 0; kt < 4; ++kt) {
            const bf16x8 a = *(const bf16x8*)&A_lds[(mt * 16 + l16) * FPAD + kt * 32 + half * 8];
            acc = __builtin_amdgcn_mfma_f32_16x16x32_bf16(a, bfrag[kt], acc, 0, 0, 0);
        }
        #pragma unroll
        for (int r = 0; r < 4; ++r) {
            int grow = b0 + mt * 16 + half * 4 + r;
            if (grow < nn) {
                size_t idx = (size_t)grow * DIM + jcol;
                out[idx] = x[idx] + alpha * (acc[r] + bias_j);
            }
        }
    }
}

extern "C" void kernel_launch(void* const* d_in, const int* in_sizes, int n_in,
                              void* d_out, int out_size, void* d_ws, size_t ws_size,
                              hipStream_t stream) {
    // inputs: x(0), edge_index(1), num_nodes(2), edge_weight(3), W(4), b(5), alpha(6)
    const float* x      = (const float*)d_in[0];
    const void*  eidx   = d_in[1];
    const float* ew     = (const float*)d_in[3];
    const float* W      = (const float*)d_in[4];
    const float* bias   = (const float*)d_in[5];
    const float* alphaP = (const float*)d_in[6];

    const int NN = in_sizes[0] / DIM;
    const int E  = in_sizes[3];

    // ws layout: aggb u16[NN*DIM] (25.6MB) | srcw u64[E] (5.1MB)
    //            | cnt int[NN] | cursor int[NN] | rowstart int[NN]
    //            | blockSums[1024] | blockOff[1024] | flags[2]   (~32 MB)
    unsigned short* aggb = (unsigned short*)d_ws;
    unsigned long long* srcw = (unsigned long long*)(aggb + (size_t)NN * DIM);
    int*   cnt       = (int*)(srcw + E);
    int*   cursor    = cnt + NN;
    int*   rowstart  = cursor + NN;
    int*   blockSums = rowstart + NN;
    int*   blockOff  = blockSums + 1024;
    int*   flags     = blockOff + 1024;

    // xb (bf16 copy of x) parks in the first half of d_out; dead once finish runs
    unsigned short* xb = (unsigned short*)d_out;
    float* out = (float*)d_out;

    int n8 = NN * DIM / 8;
    prep_kernel<<<2048, 256, 0, stream>>>(x, xb, n8, cnt, 2 * NN,
                                          (const unsigned int*)eidx, flags);

    int eblocks = (E + 255) / 256;
    hist_kernel<<<eblocks, 256, 0, stream>>>(eidx, cnt, flags, E);

    int nscan = (NN + SCAN_CHUNK - 1) / SCAN_CHUNK;             // 98 for NN=100K
    scan1_kernel<<<nscan, SCAN_TPB, 0, stream>>>(cnt, rowstart, blockSums, NN);
    scan2_kernel<<<1, 1024, 0, stream>>>(blockSums, blockOff, nscan);

    fill_kernel<<<eblocks, 256, 0, stream>>>(eidx, ew, rowstart, blockOff,
                                             cursor, srcw, flags, E);

    int gblocks = (NN + 15) / 16;                                // 16 nodes / 256-thr block
    gather_kernel<<<gblocks, 256, 0, stream>>>(xb, (const uint2*)srcw, rowstart, blockOff,
                                               aggb, NN, E);

    int fblocks = (NN + FROWS - 1) / FROWS;
    finish_kernel<<<fblocks, 512, 0, stream>>>(aggb, out, x, W, bias, alphaP, NN);
}

// Round 10
// 126.606 us; speedup vs baseline: 1.3334x; 1.1892x over previous
//
#include <hip/hip_runtime.h>
#include <hip/hip_bf16.h>

#define DIM 128
#define NPB 512                 // nodes per bucket (pow2, shift 9)
#define NPB_SHIFT 9
// NN < 2^17 (=131072) required by the 17-bit src/dst packing; harness uses 100000.

#define FROWS 64      // finish: M-tile rows per block
#define FPAD 136      // bf16 row stride in LDS: 272B -> 2-way bank alias on b128 (free)

typedef __attribute__((ext_vector_type(8))) short bf16x8;
typedef __attribute__((ext_vector_type(8))) unsigned short u16x8;
typedef __attribute__((ext_vector_type(4))) float f32x4;

__device__ __forceinline__ short f2bf(float f) {
    union { __hip_bfloat16 h; short s; } u;
    u.h = __float2bfloat16(f);   // round-to-nearest-even
    return u.s;
}
__device__ __forceinline__ float bf2f(unsigned short s) {
    union { unsigned int u; float f; } c;
    c.u = ((unsigned int)s) << 16;
    return c.f;
}

__device__ __forceinline__ int load_dst(const void* eidx, int flag64, int E, int e) {
    return flag64 ? (int)((const long long*)eidx)[E + e] : ((const int*)eidx)[E + e];
}
__device__ __forceinline__ int load_src(const void* eidx, int flag64, int E, int e) {
    return flag64 ? (int)((const long long*)eidx)[e] : ((const int*)eidx)[e];
}

// ---------------------------------------------------------------------------
// Prep (fused): zero bucket counters, cvt x f32 -> xb bf16, detect int64/int32
// edge index (values < 2^17 => int64 high words of first 128 entries all 0).
// ---------------------------------------------------------------------------
__global__ __launch_bounds__(256) void prep_kernel(
        const float* __restrict__ x, unsigned short* __restrict__ xb, int n8,
        int* __restrict__ gcnt, int nzero,
        const unsigned int* __restrict__ e, int* __restrict__ flags) {
    int stride = gridDim.x * blockDim.x;
    int t0 = blockIdx.x * blockDim.x + threadIdx.x;
    for (int t = t0; t < nzero; t += stride) gcnt[t] = 0;
    for (int t = t0; t < n8; t += stride) {
        const float4* pp = (const float4*)(x + (size_t)t * 8);
        float4 a = pp[0], b = pp[1];
        u16x8 o;
        o[0] = (unsigned short)f2bf(a.x); o[1] = (unsigned short)f2bf(a.y);
        o[2] = (unsigned short)f2bf(a.z); o[3] = (unsigned short)f2bf(a.w);
        o[4] = (unsigned short)f2bf(b.x); o[5] = (unsigned short)f2bf(b.y);
        o[6] = (unsigned short)f2bf(b.z); o[7] = (unsigned short)f2bf(b.w);
        *(u16x8*)(xb + (size_t)t * 8) = o;
    }
    if (blockIdx.x == 0 && threadIdx.x == 0) {
        int ok64 = 1;
        for (int t = 0; t < 128; ++t) {
            if (e[2 * t + 1] != 0u) { ok64 = 0; break; }
        }
        flags[0] = ok64;
    }
}

// ---------------------------------------------------------------------------
// Bucket histogram: LDS hist per block, one global atomic per (block,bucket).
// ---------------------------------------------------------------------------
__global__ __launch_bounds__(256) void histb_kernel(
        const void* __restrict__ eidx, int* __restrict__ gcnt,
        const int* __restrict__ flags, int E, int NB) {
    __shared__ int bcnt[256];
    const int tid = threadIdx.x;
    bcnt[tid] = 0;
    __syncthreads();
    int f = flags[0];
    int stride = gridDim.x * blockDim.x;
    for (int e = blockIdx.x * blockDim.x + tid; e < E; e += stride)
        atomicAdd(&bcnt[load_dst(eidx, f, E, e) >> NPB_SHIFT], 1);
    __syncthreads();
    if (tid < NB && bcnt[tid] > 0) atomicAdd(&gcnt[tid], bcnt[tid]);
}

// ---------------------------------------------------------------------------
// Bucket scan (single block): gstart = exclusive scan of gcnt; gcursor = copy;
// gstart[NB] = E.
// ---------------------------------------------------------------------------
__global__ __launch_bounds__(256) void scanb_kernel(
        const int* __restrict__ gcnt, int* __restrict__ gstart,
        int* __restrict__ gcursor, int NB, int E) {
    __shared__ int s[256];
    const int tid = threadIdx.x;
    int val = (tid < NB) ? gcnt[tid] : 0;
    s[tid] = val;
    __syncthreads();
    for (int off = 1; off < 256; off <<= 1) {
        int t = (tid >= off) ? s[tid - off] : 0;
        __syncthreads();
        s[tid] += t;
        __syncthreads();
    }
    int excl = s[tid] - val;
    if (tid < NB) { gstart[tid] = excl; gcursor[tid] = excl; }
    if (tid == NB) gstart[NB] = E;   // NB < 256 guaranteed (NN < 2^17)
}

// ---------------------------------------------------------------------------
// A1 partition: 4096 edges/block. Stage edges in LDS grouped by bucket
// (pk = w32[57:26] | dst_local[25:17] | src[16:0]), reserve per-bucket runs
// (one atomic per block,bucket), write runs contiguously -> ~1.4x write amp
// instead of 8.6x random-8B scatter.
// ---------------------------------------------------------------------------
#define A1_EPT 16
#define A1_EPB (256 * A1_EPT)
__global__ __launch_bounds__(256) void part_kernel(
        const void* __restrict__ eidx, const float* __restrict__ ew,
        int* __restrict__ gcursor, unsigned long long* __restrict__ srcw_tmp,
        const int* __restrict__ flags, int E) {
    __shared__ unsigned long long stage[A1_EPB];   // 32 KB
    __shared__ unsigned char sbid[A1_EPB];         //  4 KB
    __shared__ int bcnt[256], bscan[256], bcur[256], brun[256];
    const int tid = threadIdx.x;
    const int base = blockIdx.x * A1_EPB;
    const int f = flags[0];

    bcnt[tid] = 0;
    __syncthreads();

    unsigned long long pk[A1_EPT];
    unsigned char bid[A1_EPT];
    #pragma unroll
    for (int i = 0; i < A1_EPT; ++i) {
        int e = base + tid + i * 256;
        bid[i] = 0xFF;
        if (e < E) {
            int src = load_src(eidx, f, E, e);
            int dst = load_dst(eidx, f, E, e);
            unsigned int w = __float_as_uint(ew[e]);
            int b = dst >> NPB_SHIFT;
            pk[i] = ((unsigned long long)w << 26)
                  | ((unsigned long long)(dst & (NPB - 1)) << 17)
                  | (unsigned long long)(unsigned)src;
            bid[i] = (unsigned char)b;
            atomicAdd(&bcnt[b], 1);
        }
    }
    __syncthreads();

    // exclusive scan of bcnt (Hillis-Steele on 256)
    int val = bcnt[tid];
    bscan[tid] = val;
    __syncthreads();
    for (int off = 1; off < 256; off <<= 1) {
        int t = (tid >= off) ? bscan[tid - off] : 0;
        __syncthreads();
        bscan[tid] += t;
        __syncthreads();
    }
    int excl = bscan[tid] - val;
    __syncthreads();
    bscan[tid] = excl;        // now exclusive
    bcur[tid] = excl;
    __syncthreads();

    // rank + stage (bucket-grouped)
    #pragma unroll
    for (int i = 0; i < A1_EPT; ++i) {
        if (bid[i] != 0xFF) {
            int slot = atomicAdd(&bcur[bid[i]], 1);
            stage[slot] = pk[i];
            sbid[slot] = bid[i];
        }
    }
    // reserve global runs
    if (bcnt[tid] > 0) brun[tid] = atomicAdd(&gcursor[tid], bcnt[tid]);
    __syncthreads();

    int tot = (base + A1_EPB <= E) ? A1_EPB : (E - base);
    for (int s = tid; s < tot; s += 256) {
        int b = sbid[s];
        srcw_tmp[brun[b] + (s - bscan[b])] = stage[s];
    }
}

// ---------------------------------------------------------------------------
// A2 bucket-local sort: one block per bucket. Count per node (LDS), pair-scan
// 512, write node rowstart (coalesced), place final (w<<32|src) payloads.
// All payload writes land in the bucket's contiguous slot region from ONE
// block/XCD -> lines fill in L2 -> ~1x write amp.
// ---------------------------------------------------------------------------
__global__ __launch_bounds__(256) void sort_kernel(
        const unsigned long long* __restrict__ srcw_tmp,
        const int* __restrict__ gstart, unsigned long long* __restrict__ srcw,
        int* __restrict__ rowstart, int nn) {
    __shared__ int cnt[NPB], excl[NPB], cur[NPB], hs[256];
    const int tid = threadIdx.x;
    const int b = blockIdx.x;
    const int node0 = b << NPB_SHIFT;
    const int e0 = gstart[b], e1 = gstart[b + 1];

    cnt[tid] = 0; cnt[tid + 256] = 0;
    __syncthreads();
    for (int e = e0 + tid; e < e1; e += 256)
        atomicAdd(&cnt[(int)((srcw_tmp[e] >> 17) & (NPB - 1))], 1);
    __syncthreads();

    // pair-scan: 512 -> 256 pairs -> HS -> expand
    int c0 = cnt[2 * tid], c1 = cnt[2 * tid + 1];
    int ps = c0 + c1;
    hs[tid] = ps;
    __syncthreads();
    for (int off = 1; off < 256; off <<= 1) {
        int t = (tid >= off) ? hs[tid - off] : 0;
        __syncthreads();
        hs[tid] += t;
        __syncthreads();
    }
    int pexcl = hs[tid] - ps;
    excl[2 * tid] = pexcl;
    excl[2 * tid + 1] = pexcl + c0;
    cur[2 * tid] = pexcl;
    cur[2 * tid + 1] = pexcl + c0;
    __syncthreads();

    // node-level rowstart (coalesced)
    int nbn = nn - node0; if (nbn > NPB) nbn = NPB;
    for (int t = tid; t < nbn; t += 256)
        rowstart[node0 + t] = e0 + excl[t];

    // place payloads
    for (int e = e0 + tid; e < e1; e += 256) {
        unsigned long long pk = srcw_tmp[e];
        int dl = (int)((pk >> 17) & (NPB - 1));
        int pos = e0 + atomicAdd(&cur[dl], 1);
        srcw[pos] = ((pk >> 26) << 32) | (pk & 0x1FFFFULL);
    }
}

// ---------------------------------------------------------------------------
// Gather: 4 nodes per wave (16 lanes per node, lane owns 8 dims = 16B bf16).
// Unified contiguous segment per node; 4-edge unroll -> up to 16 row-fetches
// in flight per wave. No atomics.
// ---------------------------------------------------------------------------
__global__ __launch_bounds__(256) void gather_kernel(
        const unsigned short* __restrict__ xb, const uint2* __restrict__ srcw,
        const int* __restrict__ rowstart, unsigned short* __restrict__ aggb,
        int nn, int E) {
    int g = (blockIdx.x * blockDim.x + threadIdx.x) >> 4;   // node
    int sub16 = threadIdx.x & 15;                           // owns dims [8*sub16, +8)
    if (g >= nn) return;
    int n0 = rowstart[g];
    int n1 = (g + 1 < nn) ? rowstart[g + 1] : E;
    float acc[8] = {0.f, 0.f, 0.f, 0.f, 0.f, 0.f, 0.f, 0.f};
    int e = n0;
    for (; e + 4 <= n1; e += 4) {
        uint2 sw0 = srcw[e];
        uint2 sw1 = srcw[e + 1];
        uint2 sw2 = srcw[e + 2];
        uint2 sw3 = srcw[e + 3];
        u16x8 x0 = *(const u16x8*)(xb + (size_t)sw0.x * DIM + sub16 * 8);
        u16x8 x1 = *(const u16x8*)(xb + (size_t)sw1.x * DIM + sub16 * 8);
        u16x8 x2 = *(const u16x8*)(xb + (size_t)sw2.x * DIM + sub16 * 8);
        u16x8 x3 = *(const u16x8*)(xb + (size_t)sw3.x * DIM + sub16 * 8);
        float w0 = __uint_as_float(sw0.y);
        float w1 = __uint_as_float(sw1.y);
        float w2 = __uint_as_float(sw2.y);
        float w3 = __uint_as_float(sw3.y);
        #pragma unroll
        for (int j = 0; j < 8; ++j) {
            acc[j] = fmaf(bf2f(x0[j]), w0, acc[j]);
            acc[j] = fmaf(bf2f(x1[j]), w1, acc[j]);
            acc[j] = fmaf(bf2f(x2[j]), w2, acc[j]);
            acc[j] = fmaf(bf2f(x3[j]), w3, acc[j]);
        }
    }
    for (; e < n1; ++e) {
        uint2 sw = srcw[e];
        u16x8 xr = *(const u16x8*)(xb + (size_t)sw.x * DIM + sub16 * 8);
        float w = __uint_as_float(sw.y);
        #pragma unroll
        for (int j = 0; j < 8; ++j) acc[j] = fmaf(bf2f(xr[j]), w, acc[j]);
    }
    float inv = 1.0f / fmaxf((float)(n1 - n0), 1.0f);
    u16x8 o;
    #pragma unroll
    for (int j = 0; j < 8; ++j) o[j] = (unsigned short)f2bf(acc[j] * inv);
    *(u16x8*)(aggb + (size_t)g * DIM + sub16 * 8) = o;
}

// ---------------------------------------------------------------------------
// MFMA finish: out = x + alpha*(aggb @ W^T + b). aggb is bf16 in ws; out is
// d_out (overwrites the xb scratch parked there, which is dead by now).
// 512 threads = 8 waves; 64-row M-tile; wave w owns output cols [16w,16w+16).
// C/D map: col=lane&15, row=(lane>>4)*4+reg  [verified, learn_hip m89/m91]
// ---------------------------------------------------------------------------
__global__ __launch_bounds__(512) void finish_kernel(
        const unsigned short* __restrict__ aggb, float* __restrict__ out,
        const float* __restrict__ x, const float* __restrict__ W,
        const float* __restrict__ bias, const float* __restrict__ alphaP, int nn) {
    __shared__ alignas(16) unsigned short A_lds[FROWS * FPAD];   // 17408 B
    const int tid  = threadIdx.x;
    const int wv   = tid >> 6;          // wave 0..7
    const int lane = tid & 63;
    const int half = lane >> 4;         // 0..3 (K-group / row-group)
    const int l16  = lane & 15;         // M-row for A, N-col for B and C/D
    const int b0   = blockIdx.x * FROWS;
    const float alpha = alphaP[0];

    // ---- B-frags: W[jcol][kt*32 + half*8 .. +8] as bf16, loaded once ----
    const int jcol = wv * 16 + l16;
    bf16x8 bfrag[4];
    #pragma unroll
    for (int kt = 0; kt < 4; ++kt) {
        const float4* w4 = (const float4*)(W + (size_t)jcol * DIM + kt * 32 + half * 8);
        float4 lo = w4[0], hi = w4[1];
        bf16x8 b;
        b[0] = f2bf(lo.x); b[1] = f2bf(lo.y); b[2] = f2bf(lo.z); b[3] = f2bf(lo.w);
        b[4] = f2bf(hi.x); b[5] = f2bf(hi.y); b[6] = f2bf(hi.z); b[7] = f2bf(hi.w);
        bfrag[kt] = b;
    }
    const float bias_j = bias[jcol];

    // ---- stage 64 bf16 rows -> LDS: 1024 chunks of 16B, 2 iters ----
    #pragma unroll
    for (int it = 0; it < 2; ++it) {
        int p = it * 512 + tid;          // 0..1023
        int row = p >> 4;                // 0..63
        int c8 = p & 15;                 // 16B chunk within row
        int node = b0 + row;
        u16x8 v = {0, 0, 0, 0, 0, 0, 0, 0};
        if (node < nn) v = *(const u16x8*)(aggb + (size_t)node * DIM + c8 * 8);
        *(u16x8*)&A_lds[row * FPAD + c8 * 8] = v;
    }
    __syncthreads();

    // ---- 4 sub-tiles of 16 rows: MFMA + fused epilogue ----
    #pragma unroll
    for (int mt = 0; mt < 4; ++mt) {
        f32x4 acc = {0.f, 0.f, 0.f, 0.f};
        #pragma unroll
        for (int kt = 0; kt < 4; ++kt) {
            const bf16x8 a = *(const bf16x8*)&A_lds[(mt * 16 + l16) * FPAD + kt * 32 + half * 8];
            acc = __builtin_amdgcn_mfma_f32_16x16x32_bf16(a, bfrag[kt], acc, 0, 0, 0);
        }
        #pragma unroll
        for (int r = 0; r < 4; ++r) {
            int grow = b0 + mt * 16 + half * 4 + r;
            if (grow < nn) {
                size_t idx = (size_t)grow * DIM + jcol;
                out[idx] = x[idx] + alpha * (acc[r] + bias_j);
            }
        }
    }
}

extern "C" void kernel_launch(void* const* d_in, const int* in_sizes, int n_in,
                              void* d_out, int out_size, void* d_ws, size_t ws_size,
                              hipStream_t stream) {
    // inputs: x(0), edge_index(1), num_nodes(2), edge_weight(3), W(4), b(5), alpha(6)
    const float* x      = (const float*)d_in[0];
    const void*  eidx   = d_in[1];
    const float* ew     = (const float*)d_in[3];
    const float* W      = (const float*)d_in[4];
    const float* bias   = (const float*)d_in[5];
    const float* alphaP = (const float*)d_in[6];

    const int NN = in_sizes[0] / DIM;       // < 2^17 required (harness: 100000)
    const int E  = in_sizes[3];
    const int NB = (NN + NPB - 1) / NPB;    // 196 buckets

    // ws layout: aggb u16[NN*DIM] (25.6MB) | srcw u64[E] | srcw_tmp u64[E]
    //            | rowstart int[NN] | gcnt[256] | gstart[257] | gcursor[256]
    //            | flags[2]   (~36.7 MB)
    unsigned short* aggb = (unsigned short*)d_ws;
    unsigned long long* srcw     = (unsigned long long*)(aggb + (size_t)NN * DIM);
    unsigned long long* srcw_tmp = srcw + E;
    int* rowstart = (int*)(srcw_tmp + E);
    int* gcnt     = rowstart + NN;
    int* gstart   = gcnt + 256;
    int* gcursor  = gstart + 257;
    int* flags    = gcursor + 256;

    // xb (bf16 copy of x) parks in the first half of d_out; dead once finish runs
    unsigned short* xb = (unsigned short*)d_out;
    float* out = (float*)d_out;

    int n8 = NN * DIM / 8;
    prep_kernel<<<2048, 256, 0, stream>>>(x, xb, n8, gcnt, 256,
                                          (const unsigned int*)eidx, flags);

    histb_kernel<<<1024, 256, 0, stream>>>(eidx, gcnt, flags, E, NB);

    scanb_kernel<<<1, 256, 0, stream>>>(gcnt, gstart, gcursor, NB, E);

    int a1blocks = (E + A1_EPB - 1) / A1_EPB;   // 157
    part_kernel<<<a1blocks, 256, 0, stream>>>(eidx, ew, gcursor, srcw_tmp, flags, E);

    sort_kernel<<<NB, 256, 0, stream>>>(srcw_tmp, gstart, srcw, rowstart, NN);

    int gblocks = (NN + 15) / 16;               // 16 nodes / 256-thr block
    gather_kernel<<<gblocks, 256, 0, stream>>>(xb, (const uint2*)srcw, rowstart,
                                               aggb, NN, E);

    int fblocks = (NN + FROWS - 1) / FROWS;
    finish_kernel<<<fblocks, 512, 0, stream>>>(aggb, out, x, W, bias, alphaP, NN);
}